// Round 9
// baseline (178.349 us; speedup 1.0000x reference)
//
#include <hip/hip_runtime.h>
#include <math.h>

#define Bsz 2048
#define Ddim 32
#define Nsz 8192
#define Kk 30
#define TPB 256
#define ROWS 16                  // i-rows per block, staged in LDS (broadcast reads)
#define JSL 8                    // j-slices; each block covers TPB j's (one per thread)
#define JT (Bsz / JSL)           // 256 j per block == TPB
#define NBLK ((Bsz / ROWS) * JSL) // 128 * 8 = 1024 blocks = 4/CU at 128 VGPR
#define NW (Nsz / 32)            // 256 bitset words per row

// R8 post-mortem: VGPR=128 as planned, yet FETCH 146MB / WRITE 296MB of
// scratch traffic remained. Only consistent explanation: the compiler
// PROMOTES the zish LDS reads to registers -- zish is written once,
// barriered, then read at static addresses in a fully-unrolled loop
// (16 rows x 8 float4 = 512 dwords of promoted values vs a 128-reg budget
// -> allocator spills the promoted temps; ~430 dwords/thread moved matches
// the measured 460MB). R5 was clean precisely because its j-tile was
// rewritten each chunk (unpromotable) and its i-rows were explicit
// registers sized to fit. Fix: asm volatile memory fence at the top of
// each unrolled d-iteration -- LDS loads can't be hoisted/merged across a
// memory clobber, so each iteration re-reads its 16 broadcast float4s
// (ds_read_b128, lane-uniform = conflict-free) and live state stays ~115
// dwords inside the proven 128-VGPR allocation. Also: transpose-reduce
// rotation gets +4*gsel so the 4 16-lane groups of a wave stop colliding
// on banks (sum unchanged). Everything else identical to R8.
__global__ __launch_bounds__(TPB, 2) void softnp_main(
    const float* __restrict__ z,
    const int*   __restrict__ pre_knn,
    const int*   __restrict__ samp,
    float*       __restrict__ wsden,   // [JSL][Bsz] partial denominators
    float*       __restrict__ wsnum)   // [JSL][Bsz] partial masked numerators
{
    __shared__ unsigned bits[NW][ROWS];   // 16 KB; reused as reduce scratch later
    __shared__ float    zish[ROWS * Ddim];// 2 KB
    __shared__ float    sish[ROWS];
    __shared__ int      rowsi[ROWS];

    const int t  = threadIdx.x;
    const int g  = blockIdx.x >> 3;       // row-group (128 groups)
    const int s  = blockIdx.x & 7;        // j-slice: bid&7 ~ XCD -> slice/XCD locality
    const int i0 = g * ROWS;
    const int j  = s * JT + t;            // this thread's single j

    // ---- front-load ALL independent global traffic (MLP burst) ----
    float4 zj[8];
    const float4* zg = (const float4*)z;
    #pragma unroll
    for (int d = 0; d < 8; ++d) zj[d] = zg[(size_t)j * 8 + d];
    const int sj = samp[j];

    // stage: zero bitsets (4096 words / 256 thr), z_i rows, row ids
    #pragma unroll
    for (int c = 0; c < (NW * ROWS) / TPB; ++c)
        ((unsigned*)bits)[t + c * TPB] = 0u;
    zish[t]       = z[(size_t)i0 * Ddim + t];        // rows 0..7
    zish[t + TPB] = z[(size_t)i0 * Ddim + t + TPB];  // rows 8..15
    if (t < ROWS) rowsi[t] = samp[i0 + t];
    __syncthreads();

    // ---- fill bitsets: 16 rows x 30 entries = 480, 2 per thread ----
    #pragma unroll
    for (int c = 0; c < 2; ++c) {
        const int idx = t + c * TPB;
        if (idx < ROWS * Kk) {
            const int r  = idx / Kk, k = idx - r * Kk;
            const int id = pre_knn[(size_t)rowsi[r] * Kk + k];
            atomicOr(&bits[id >> 5][r], 1u << (id & 31));
        }
    }
    // |z_i|^2 for the 16 rows (t<16), reads zish staged above
    if (t < ROWS) {
        float a = 0.f;
        #pragma unroll
        for (int d = 0; d < Ddim; ++d) {
            const float w = zish[t * Ddim + d];
            a += w * w;
        }
        sish[t] = a;
    }
    __syncthreads();   // bits + sish ready

    // ---- dot loop: LDS-broadcast + FMA; fence stops LDS->reg promotion ----
    float dot[ROWS];
    #pragma unroll
    for (int r = 0; r < ROWS; ++r) dot[r] = 0.f;
    float sj2 = 0.f;
    const float4* z4s = (const float4*)zish;
    #pragma unroll
    for (int d = 0; d < 8; ++d) {
        asm volatile("" ::: "memory");       // anti-promotion fence (see header)
        const float4 v = zj[d];
        sj2 += v.x * v.x + v.y * v.y + v.z * v.z + v.w * v.w;
        #pragma unroll
        for (int r = 0; r < ROWS; ++r) {
            const float4 w = z4s[r * 8 + d]; // lane-uniform broadcast ds_read_b128
            dot[r] += w.x * v.x + w.y * v.y + w.z * v.z + w.w * v.w;
        }
    }

    // ---- mask bits for this j across 16 rows -> ONE packed register ----
    const int wword = sj >> 5, wbit = sj & 31;
    const uint4* b4 = (const uint4*)bits;
    const uint4 q0 = b4[wword * 4 + 0], q1 = b4[wword * 4 + 1];
    const uint4 q2 = b4[wword * 4 + 2], q3 = b4[wword * 4 + 3];
    const unsigned bsel[ROWS] = {q0.x, q0.y, q0.z, q0.w, q1.x, q1.y, q1.z, q1.w,
                                 q2.x, q2.y, q2.z, q2.w, q3.x, q3.y, q3.z, q3.w};
    unsigned nmask = 0u;
    const int dr = j - i0;               // diag <=> r == dr
    float dval[ROWS];
    #pragma unroll
    for (int r = 0; r < ROWS; ++r) {
        const float d2 = fmaxf(sish[r] + sj2 - 2.f * dot[r], 0.f);
        const bool diag = (r == dr);
        const float e = diag ? 0.f : __expf(-sqrtf(d2));
        dval[r] = e;
        if (!diag && ((bsel[r] >> wbit) & 1u)) nmask |= 1u << r;
    }

    // ---- reduce 256 threads -> 16 row sums, via LDS transpose ----
    // (reuse the dead 16 KB bitset region; rotation (k+m+4*gsel)&15 keeps the
    //  sum intact and spreads the wave's 4 gsel-groups across distinct banks)
    __syncthreads();                     // all bits reads complete
    float* sc = (float*)bits;            // [ROWS][TPB] = 4096 floats
    const int gsel = t >> 4, m = t & 15; // 16 groups x 16 lanes; group = row

    #pragma unroll
    for (int r = 0; r < ROWS; ++r) sc[r * TPB + t] = dval[r];
    __syncthreads();
    float a = 0.f;
    #pragma unroll
    for (int k = 0; k < 16; ++k)
        a += sc[gsel * TPB + m * 16 + ((k + m + 4 * gsel) & 15)];
    a += __shfl_xor(a, 1, 64); a += __shfl_xor(a, 2, 64);
    a += __shfl_xor(a, 4, 64); a += __shfl_xor(a, 8, 64);
    if (m == 0) wsden[s * Bsz + i0 + gsel] = a;   // pure overwrite

    __syncthreads();
    #pragma unroll
    for (int r = 0; r < ROWS; ++r)
        sc[r * TPB + t] = ((nmask >> r) & 1u) ? dval[r] : 0.f;
    __syncthreads();
    float b = 0.f;
    #pragma unroll
    for (int k = 0; k < 16; ++k)
        b += sc[gsel * TPB + m * 16 + ((k + m + 4 * gsel) & 15)];
    b += __shfl_xor(b, 1, 64); b += __shfl_xor(b, 2, 64);
    b += __shfl_xor(b, 4, 64); b += __shfl_xor(b, 8, 64);
    if (m == 0) wsnum[s * Bsz + i0 + gsel] = b;   // pure overwrite
}

// Tail: combine 8 slice-partials per row, 2048 logs, one scalar. ~128 KB read.
__global__ __launch_bounds__(TPB) void softnp_final(
    const float* __restrict__ wsden,
    const float* __restrict__ wsnum,
    float*       __restrict__ out)
{
    __shared__ float rl[4], rc[4];
    const int t = threadIdx.x;
    float loss = 0.f, vcnt = 0.f;
    #pragma unroll
    for (int c = 0; c < Bsz / TPB; ++c) {
        const int i = t + c * TPB;
        float D = 0.f, N = 0.f;
        #pragma unroll
        for (int sl = 0; sl < JSL; ++sl) {
            D += wsden[sl * Bsz + i];
            N += wsnum[sl * Bsz + i];
        }
        if (N > 0.f) {            // valid <=> any masked neighbor (no underflow:
            loss -= __logf(N / D + 1e-8f);   // exp(-d) >= ~e^-16 for this data)
            vcnt += 1.f;
        }
    }
    #pragma unroll
    for (int off = 32; off > 0; off >>= 1) {
        loss += __shfl_xor(loss, off, 64);
        vcnt += __shfl_xor(vcnt, off, 64);
    }
    const int lane = t & 63, wv = t >> 6;
    if (lane == 0) { rl[wv] = loss; rc[wv] = vcnt; }
    __syncthreads();
    if (t == 0) {
        const float L = rl[0] + rl[1] + rl[2] + rl[3];
        const float C = rc[0] + rc[1] + rc[2] + rc[3];
        out[0] = (C > 0.f) ? L / C : 0.f;
    }
}

extern "C" void kernel_launch(void* const* d_in, const int* in_sizes, int n_in,
                              void* d_out, int out_size, void* d_ws, size_t ws_size,
                              hipStream_t stream)
{
    const float* z       = (const float*)d_in[0];
    const int*   pre_knn = (const int*)d_in[1];
    const int*   samp    = (const int*)d_in[2];
    float*       out     = (float*)d_out;
    float*       wsden   = (float*)d_ws;             // [JSL][Bsz]
    float*       wsnum   = wsden + JSL * Bsz;        // [JSL][Bsz]

    // No memset: every (slice,row) ws slot is overwritten by softnp_main.
    softnp_main<<<dim3(NBLK), dim3(TPB), 0, stream>>>(z, pre_knn, samp, wsden, wsnum);
    softnp_final<<<dim3(1), dim3(TPB), 0, stream>>>(wsden, wsnum, out);
}